// Round 12
// baseline (243.022 us; speedup 1.0000x reference)
//
#include <hip/hip_runtime.h>
#include <hip/hip_bf16.h>

#define TB 2048
#define NH 16
#define HD 64
#define NE 1024
#define NB 4
#define BHD (NB * NH)      // 64 batch*heads
#define MTOK (NB * TB)     // 8192

typedef __attribute__((ext_vector_type(8))) short short8;
typedef __attribute__((ext_vector_type(4))) float f32x4;
typedef __attribute__((ext_vector_type(16))) float f32x16;
typedef __attribute__((ext_vector_type(4))) unsigned int u32x4;

static __device__ __forceinline__ unsigned short f2bf(float f) {
  __hip_bfloat16 h = __float2bfloat16(f);
  return __builtin_bit_cast(unsigned short, h);
}

#define GLDS(g, l)                                                              \
  __builtin_amdgcn_global_load_lds((const __attribute__((address_space(1))) void*)(g), \
                                   (__attribute__((address_space(3))) void*)(l), 16, 0, 0)

// ---------------- f32 -> bf16 convert (vectorized) ----------------
__global__ __launch_bounds__(256) void cvt_kernel(const float* __restrict__ in,
                                                  unsigned short* __restrict__ out,
                                                  int n4) {
  int i = blockIdx.x * blockDim.x + threadIdx.x;
  if (i >= n4) return;
  float4 v = reinterpret_cast<const float4*>(in)[i];
  ushort4 o;
  o.x = f2bf(v.x); o.y = f2bf(v.y); o.z = f2bf(v.z); o.w = f2bf(v.w);
  reinterpret_cast<ushort4*>(out)[i] = o;
}

// ---------------- RoPE cos/sin table: tab[t*32+j] = (cos, sin)(t * 10000^(-j/32)) ----------------
__global__ __launch_bounds__(256) void rope_tab_kernel(float2* __restrict__ tab) {
  int i = blockIdx.x * 256 + threadIdx.x;  // 0..65535
  int t = i >> 5, j = i & 31;
  float ang = (float)t * __builtin_exp2f(-(float)j * 0.41524101186092029f);
  float sv, cv;
  sincosf(ang, &sv, &cv);
  tab[i] = make_float2(cv, sv);
}

// ---------------- GEMM C = A * B^T, BK=32 triple-buffered counted-vmcnt K-loop --------
// T4: stage tile t+2 during iter t; end-of-iter s_waitcnt vmcnt(4) retires tile
// t+1 while t+2's 4 loads stay IN FLIGHT across the barrier (never drain to 0).
// 48KB LDS -> 3 blocks/CU (TLP preserved). LDS layout pair-interleaved:
// element (row,k8=seg) lives at byte (row>>1)*128 + ((seg*2+(row&1))^((row>>1)&7))*16
// -> conflict-free ds_read_b128 (2-way = free); staging stays gload_lds-linear
// via pre-swizzled global source. lgkmcnt(0)+sched_barrier before each barrier
// (compiler hoists reg-only MFMA past asm waits otherwise).
// EPI==1 epilogue writes K/V in FRAGMENT-MAJOR layout (4KB per 32-kv block):
//   K2 block idx = (d>>4)*512 + ((d>>3)&1)*256 + (t&31)*8 + (d&7)
//   V2 block idx = ((d>>5)*2 + ((t&31)>>4))*512 + ((t>>3)&1)*256 + (d&31)*8 + (t&7)
template <int EPI>  // 0: plain f32 C store; 1: QKV epilogue (RoPE + scatter)
__global__ __launch_bounds__(256) void gemm_bt(
    const unsigned short* __restrict__ Am, const unsigned short* __restrict__ Bm,
    float* __restrict__ Cout, unsigned short* __restrict__ Qo,
    unsigned short* __restrict__ Ko, unsigned short* __restrict__ Vt,
    const float2* __restrict__ Tab, int Mdim, int Ndim, int Kdim) {
  __shared__ unsigned short As[3][4096];  // 8KB per buffer (128 x 32 bf16)
  __shared__ unsigned short Bs[3][4096];

  const int tid = threadIdx.x;
  const int lane = tid & 63;
  const int w = tid >> 6;
  const int wr = w >> 1;
  const int wc = w & 1;

  // XCD-aware bijective swizzle (grid counts are multiples of 8)
  const int nwg = gridDim.x * gridDim.y;
  int bid = blockIdx.y * gridDim.x + blockIdx.x;
  const int cpx = nwg >> 3;
  bid = (bid & 7) * cpx + (bid >> 3);
  const int m0 = (bid / gridDim.x) * 128;
  const int n0 = (bid % gridDim.x) * 128;

  const int col16 = lane & 15;
  const int seg = lane >> 4;

  f32x4 acc[4][4];
#pragma unroll
  for (int i = 0; i < 4; ++i)
#pragma unroll
    for (int j = 0; j < 4; ++j) acc[i][j] = f32x4{0.f, 0.f, 0.f, 0.f};

  const int NKT = Kdim >> 5;  // K-tiles of 32 (=32 for K=1024)

  // stage one 128x32 A-tile + B-tile (4 loads/thread) for K-tile tt -> buffer bb
#define STAGE32(bb, tt)                                                         \
  {                                                                             \
    _Pragma("unroll") for (int i_ = 0; i_ < 2; ++i_) {                          \
      const int c_ = i_ * 256 + tid;   /* slot 0..511 */                        \
      const int p_ = c_ >> 3;          /* row pair 0..63 */                     \
      const int j_ = (c_ & 7) ^ (p_ & 7);                                       \
      const int row_ = p_ * 2 + (j_ & 1);                                       \
      const int ch_ = j_ >> 1;         /* 16B k-chunk 0..3 */                   \
      GLDS(Am + (size_t)(m0 + row_) * Kdim + (tt) * 32 + ch_ * 8,               \
           &As[bb][c_ * 8]);                                                    \
      GLDS(Bm + (size_t)(n0 + row_) * Kdim + (tt) * 32 + ch_ * 8,               \
           &Bs[bb][c_ * 8]);                                                    \
    }                                                                           \
  }

#define GITER(tt, bc, bs)                                                       \
  {                                                                             \
    const int tp_ = ((tt) + 2 < NKT) ? (tt) + 2 : NKT - 1;                      \
    STAGE32(bs, tp_);                                                           \
    short8 af[4], bf2[4];                                                       \
    _Pragma("unroll") for (int mi = 0; mi < 4; ++mi) {                          \
      const int row = wr * 64 + mi * 16 + col16;                                \
      af[mi] = *reinterpret_cast<const short8*>(                                \
          reinterpret_cast<const char*>(&As[bc][0]) + (row >> 1) * 128 +        \
          ((((seg << 1) | (row & 1)) ^ ((row >> 1) & 7)) << 4));                \
    }                                                                           \
    _Pragma("unroll") for (int ni = 0; ni < 4; ++ni) {                          \
      const int row = wc * 64 + ni * 16 + col16;                                \
      bf2[ni] = *reinterpret_cast<const short8*>(                               \
          reinterpret_cast<const char*>(&Bs[bc][0]) + (row >> 1) * 128 +        \
          ((((seg << 1) | (row & 1)) ^ ((row >> 1) & 7)) << 4));                \
    }                                                                           \
    _Pragma("unroll") for (int mi = 0; mi < 4; ++mi)                            \
      _Pragma("unroll") for (int ni = 0; ni < 4; ++ni)                          \
        acc[mi][ni] = __builtin_amdgcn_mfma_f32_16x16x32_bf16(                  \
            af[mi], bf2[ni], acc[mi][ni], 0, 0, 0);                             \
    asm volatile("s_waitcnt vmcnt(4) lgkmcnt(0)" ::: "memory");                 \
    __builtin_amdgcn_sched_barrier(0);                                          \
    __builtin_amdgcn_s_barrier();                                               \
    __builtin_amdgcn_sched_barrier(0);                                          \
  }

  // prologue: stage tiles 0,1; wait tile 0 (vmcnt(4) leaves tile 1 in flight)
  STAGE32(0, 0);
  STAGE32(1, 1);
  asm volatile("s_waitcnt vmcnt(4)" ::: "memory");
  __builtin_amdgcn_sched_barrier(0);
  __builtin_amdgcn_s_barrier();
  __builtin_amdgcn_sched_barrier(0);

  int t = 0;
  for (; t + 3 <= NKT; t += 3) {
    GITER(t, 0, 2);
    GITER(t + 1, 1, 0);
    GITER(t + 2, 2, 1);
  }
  for (; t < NKT; ++t) {
    const int b_ = t % 3, s_ = (t + 2) % 3;
    GITER(t, b_, s_);
  }
#undef STAGE32
#undef GITER

  if (EPI == 0) {
#pragma unroll
    for (int mi = 0; mi < 4; ++mi)
#pragma unroll
      for (int ni = 0; ni < 4; ++ni) {
        const int gn = n0 + wc * 64 + ni * 16 + col16;
#pragma unroll
        for (int r = 0; r < 4; ++r) {
          const int gm = m0 + wr * 64 + mi * 16 + seg * 4 + r;
          Cout[(size_t)gm * Ndim + gn] = acc[mi][ni][r];
        }
      }
  } else {
    // qkv: n in [0,1024)=Q, [1024,2048)=K, [2048,3072)=V. 128|1024 so sec uniform.
    const int sec = n0 >> 10;
    const int cbase = (n0 & 1023) + wc * 64;  // multiple of 64
    const int h = cbase >> 6;
#pragma unroll
    for (int mi = 0; mi < 4; ++mi)
#pragma unroll
      for (int ni = 0; ni < 4; ++ni) {
        const int d = ni * 16 + col16;  // 0..63 head dim
        if (sec == 2) {
          // V2 fragment-major: 4 consecutive t (same d) stay contiguous (8B store)
          const int gm0 = m0 + wr * 64 + mi * 16 + seg * 4;
          const int b = gm0 >> 11;
          const int t0 = gm0 & 2047;
          ushort4 pv;
          pv.x = f2bf(acc[mi][ni][0]);
          pv.y = f2bf(acc[mi][ni][1]);
          pv.z = f2bf(acc[mi][ni][2]);
          pv.w = f2bf(acc[mi][ni][3]);
          const size_t vaddr = (size_t)(b * NH + h) * TB * HD + (size_t)(t0 >> 5) * 2048 +
                               ((d >> 5) * 2 + ((t0 & 31) >> 4)) * 512 +
                               ((t0 >> 3) & 1) * 256 + (d & 31) * 8 + (t0 & 7);
          *reinterpret_cast<ushort4*>(Vt + vaddr) = pv;
        } else {
          // RoPE via precomputed table: angle a_d = t * 10000^(-(d%32)/32)
          const float sgn = (d & 1) ? 1.f : -1.f;
          const int j = d & 31;
#pragma unroll
          for (int r = 0; r < 4; ++r) {
            const int gm = m0 + wr * 64 + mi * 16 + seg * 4 + r;
            const int b = gm >> 11;
            const int t2 = gm & 2047;
            const float v = acc[mi][ni][r];
            const float p = __shfl_xor(v, 1);  // pair partner (adjacent col)
            const float2 csv = Tab[t2 * 32 + j];
            float rot = v * csv.x + sgn * p * csv.y;
            if (sec == 0) {
              // fold 1/sqrt(D) AND log2(e) into Q so attn softmax can use exp2
              rot *= 0.18033688011112042f;  // 0.125 * log2(e)
              Qo[((size_t)(b * NH + h) * TB + t2) * HD + d] = f2bf(rot);
            } else {
              // K2 fragment-major
              const size_t kaddr = (size_t)(b * NH + h) * TB * HD +
                                   (size_t)(t2 >> 5) * 2048 + (d >> 4) * 512 +
                                   ((d >> 3) & 1) * 256 + (t2 & 31) * 8 + (d & 7);
              Ko[kaddr] = f2bf(rot);
            }
          }
        }
      }
  }
}

// ---------------- causal flash attention v8 (r10, unchanged) ----------------
// One wave per 32-q tile, 1024 blocks x 4 waves (4096 waves). Natural VGPR ->
// 4 waves/SIMD resident without spills. LPT order: longest qt first. XCD pinned:
// bx%8 == (bx&15)%8 so each XCD serves the same 8 bh (4MB K2+V2 = one L2).
__global__ __launch_bounds__(256) void attn_kernel(
    const unsigned short* __restrict__ Q, const unsigned short* __restrict__ K2,
    const unsigned short* __restrict__ V2, unsigned short* __restrict__ Ao) {
  const int tid = threadIdx.x;
  const int lane = tid & 63;
  const int w = tid >> 6;
  const int bx = blockIdx.x;
  const int qt = 63 - (bx >> 4);        // longest q-tiles dispatched first
  const int bh = ((bx & 15) << 2) | w;  // 4 bh per block, all same qt
  const int q0 = qt << 5;
  const int l31 = lane & 31;
  const int hi = lane >> 5;
  const int qm = l31 - 4 * hi;          // diag mask: kill reg r if rowbase(r) > qm

  const unsigned short* Qb = Q + (size_t)bh * TB * HD;
  const unsigned short* K2b = K2 + (size_t)bh * TB * HD;
  const unsigned short* V2b = V2 + (size_t)bh * TB * HD;
  const int fo = hi * 256 + l31 * 8;    // per-lane offset within a fragment group

  const int batch = bh >> 4;
  const int h = bh & 15;

#define MASKDIAG(st)                                                            \
  { _Pragma("unroll") for (int r = 0; r < 16; ++r) {                            \
      const int rowb = (r & 3) + 8 * (r >> 2);                                  \
      if (rowb > qm) st[r] = -1e30f; } }

#define PVTILE(st, V0, V1, V2x, V3)                                             \
  {                                                                             \
    unsigned int wd[8];                                                         \
    _Pragma("unroll") for (int i = 0; i < 8; ++i) {                             \
      unsigned int t_;                                                          \
      asm("v_cvt_pk_bf16_f32 %0, %1, %2"                                        \
          : "=v"(t_) : "v"(st[2 * i]), "v"(st[2 * i + 1]));                     \
      wd[i] = t_;                                                               \
    }                                                                           \
    asm("v_permlane32_swap_b32 %0, %1" : "+v"(wd[0]), "+v"(wd[2]));             \
    asm("v_permlane32_swap_b32 %0, %1" : "+v"(wd[1]), "+v"(wd[3]));             \
    asm("v_permlane32_swap_b32 %0, %1" : "+v"(wd[4]), "+v"(wd[6]));             \
    asm("v_permlane32_swap_b32 %0, %1" : "+v"(wd[5]), "+v"(wd[7]));             \
    u32x4 f0 = {wd[0], wd[1], wd[2], wd[3]};                                    \
    u32x4 f1 = {wd[4], wd[5], wd[6], wd[7]};                                    \
    short8 p0 = __builtin_bit_cast(short8, f0);                                 \
    short8 p1 = __builtin_bit_cast(short8, f1);                                 \
    __builtin_amdgcn_s_setprio(1);                                              \
    o0 = __builtin_amdgcn_mfma_f32_32x32x16_bf16(V0, p0, o0, 0, 0, 0);          \
    o1 = __builtin_amdgcn_mfma_f32_32x32x16_bf16(V1, p0, o1, 0, 0, 0);          \
    o0 = __builtin_amdgcn_mfma_f32_32x32x16_bf16(V2x, p1, o0, 0, 0, 0);         \
    o1 = __builtin_amdgcn_mfma_f32_32x32x16_bf16(V3, p1, o1, 0, 0, 0);          \
    __builtin_amdgcn_s_setprio(0);                                              \
  }

  short8 qf[4];
#pragma unroll
  for (int s = 0; s < 4; ++s)
    qf[s] = *reinterpret_cast<const short8*>(
        Qb + (size_t)(q0 + l31) * HD + hi * 8 + s * 16);

  f32x16 o0, o1;
#pragma unroll
  for (int r = 0; r < 16; ++r) { o0[r] = 0.f; o1[r] = 0.f; }
  float mrow = -1e30f, lsum = 0.f;

  // preload K fragments for iter 0 (kv blocks 0 and 1) — coalesced
  short8 kf0[4], kf1[4];
#pragma unroll
  for (int s = 0; s < 4; ++s)
    kf0[s] = *reinterpret_cast<const short8*>(K2b + s * 512 + fo);
  if (q0 >= 32)
#pragma unroll
    for (int s = 0; s < 4; ++s)
      kf1[s] = *reinterpret_cast<const short8*>(K2b + 2048 + s * 512 + fo);

  const int LI = qt >> 1;
  for (int kt = 0; kt <= LI; ++kt) {
    const int kv0 = kt << 6;
    const bool two = (kv0 + 32 <= q0);

    // QK^T (S^T accumulate) with preloaded K frags
    f32x16 s0, s1;
#pragma unroll
    for (int r = 0; r < 16; ++r) { s0[r] = 0.f; s1[r] = 0.f; }
    __builtin_amdgcn_s_setprio(1);
#pragma unroll
    for (int s = 0; s < 4; ++s)
      s0 = __builtin_amdgcn_mfma_f32_32x32x16_bf16(kf0[s], qf[s], s0, 0, 0, 0);
    if (two)
#pragma unroll
      for (int s = 0; s < 4; ++s)
        s1 = __builtin_amdgcn_mfma_f32_32x32x16_bf16(kf1[s], qf[s], s1, 0, 0, 0);
    __builtin_amdgcn_s_setprio(0);

    // V frags for THIS iter (fragment-major, coalesced; consumed after softmax)
    const unsigned short* Va = V2b + (size_t)(2 * kt) * 2048 + fo;
    short8 va0 = *reinterpret_cast<const short8*>(Va);
    short8 va1 = *reinterpret_cast<const short8*>(Va + 1024);
    short8 va2 = *reinterpret_cast<const short8*>(Va + 512);
    short8 va3 = *reinterpret_cast<const short8*>(Va + 1536);
    short8 vb0, vb1, vb2, vb3;
    if (two) {
      const unsigned short* Vbp = Va + 2048;
      vb0 = *reinterpret_cast<const short8*>(Vbp);
      vb1 = *reinterpret_cast<const short8*>(Vbp + 1024);
      vb2 = *reinterpret_cast<const short8*>(Vbp + 512);
      vb3 = *reinterpret_cast<const short8*>(Vbp + 1536);
    }

    // K frags for NEXT iter (coalesced prefetch)
    if (kt < LI) {
      const unsigned short* Kn = K2b + (size_t)(2 * kt + 2) * 2048;
#pragma unroll
      for (int s = 0; s < 4; ++s)
        kf0[s] = *reinterpret_cast<const short8*>(Kn + s * 512 + fo);
      if (kv0 + 96 <= q0)
#pragma unroll
        for (int s = 0; s < 4; ++s)
          kf1[s] = *reinterpret_cast<const short8*>(Kn + 2048 + s * 512 + fo);
    }

    // causal mask on the diagonal 32x32 tile
    if (kv0 == q0) MASKDIAG(s0);
    if (two && (kv0 + 32 == q0)) MASKDIAG(s1);

    // online softmax (exp2 domain; Q pre-scaled by 0.125*log2e), defer-max,
    // tree-shaped reductions.
    float mx[8];
#pragma unroll
    for (int i = 0; i < 8; ++i) mx[i] = fmaxf(s0[2 * i], s0[2 * i + 1]);
    if (two)
#pragma unroll
      for (int i = 0; i < 8; ++i)
        mx[i] = fmaxf(mx[i], fmaxf(s1[2 * i], s1[2 * i + 1]));
#pragma unroll
    for (int i = 0; i < 4; ++i) mx[i] = fmaxf(mx[i], mx[i + 4]);
    float pm = fmaxf(fmaxf(mx[0], mx[1]), fmaxf(mx[2], mx[3]));
    pm = fmaxf(pm, __shfl_xor(pm, 32));
    if (!__all(pm - mrow <= 8.f)) {
      const float mn = fmaxf(mrow, pm);
      const float fs = __builtin_exp2f(mrow - mn);
      mrow = mn;
      lsum *= fs;
#pragma unroll
      for (int r = 0; r < 16; ++r) { o0[r] *= fs; o1[r] *= fs; }
    }
    float sm[8];
#pragma unroll
    for (int i = 0; i < 8; ++i) {
      s0[2 * i] = __builtin_exp2f(s0[2 * i] - mrow);
      s0[2 * i + 1] = __builtin_exp2f(s0[2 * i + 1] - mrow);
      sm[i] = s0[2 * i] + s0[2 * i + 1];
    }
    if (two)
#pragma unroll
      for (int i = 0; i < 8; ++i) {
        s1[2 * i] = __builtin_exp2f(s1[2 * i] - mrow);
        s1[2 * i + 1] = __builtin_exp2f(s1[2 * i + 1] - mrow);
        sm[i] += s1[2 * i] + s1[2 * i + 1];
      }
#pragma unroll
    for (int i = 0; i < 4; ++i) sm[i] += sm[i + 4];
    float rs = (sm[0] + sm[1]) + (sm[2] + sm[3]);
    rs += __shfl_xor(rs, 32);
    lsum += rs;

    PVTILE(s0, va0, va1, va2, va3);
    if (two) PVTILE(s1, vb0, vb1, vb2, vb3);
  }

  // epilogue: normalize (lsum lane-uniform per q) and store bf16 to Ao[B][T][E]
  const float inv = 1.f / lsum;
  unsigned short* Aor = Ao + ((size_t)(batch * TB + q0 + l31)) * NE + (h << 6);
#pragma unroll
  for (int dt = 0; dt < 2; ++dt) {
#pragma unroll
    for (int qd = 0; qd < 4; ++qd) {
      ushort4 pk;
      pk.x = f2bf((dt ? o1[4 * qd + 0] : o0[4 * qd + 0]) * inv);
      pk.y = f2bf((dt ? o1[4 * qd + 1] : o0[4 * qd + 1]) * inv);
      pk.z = f2bf((dt ? o1[4 * qd + 2] : o0[4 * qd + 2]) * inv);
      pk.w = f2bf((dt ? o1[4 * qd + 3] : o0[4 * qd + 3]) * inv);
      *reinterpret_cast<ushort4*>(Aor + dt * 32 + 8 * qd + 4 * hi) = pk;
    }
  }
#undef MASKDIAG
#undef PVTILE
}

// ---------------- launch ----------------
extern "C" void kernel_launch(void* const* d_in, const int* in_sizes, int n_in,
                              void* d_out, int out_size, void* d_ws, size_t ws_size,
                              hipStream_t stream) {
  const float* x = (const float*)d_in[0];
  const float* w_attn = (const float*)d_in[1];
  const float* w_proj = (const float*)d_in[2];
  float* out = (float*)d_out;
  char* ws = (char*)d_ws;

  const size_t SZ_XB = (size_t)MTOK * NE * 2;        // 16 MiB
  const size_t SZ_WA = (size_t)3 * NE * NE * 2;      // 6 MiB
  const size_t SZ_WP = (size_t)NE * NE * 2;          // 2 MiB
  const size_t SZ_T = (size_t)BHD * TB * HD * 2;     // 16 MiB

  unsigned short* xb = (unsigned short*)(ws);
  unsigned short* wab = (unsigned short*)(ws + SZ_XB);
  unsigned short* wpb = (unsigned short*)(ws + SZ_XB + SZ_WA);
  unsigned short* Qs = (unsigned short*)(ws + SZ_XB + SZ_WA + SZ_WP);
  unsigned short* K2 = (unsigned short*)(ws + SZ_XB + SZ_WA + SZ_WP + SZ_T);
  unsigned short* V2 = (unsigned short*)(ws + SZ_XB + SZ_WA + SZ_WP + 2 * SZ_T);
  unsigned short* Ao = (unsigned short*)(ws + SZ_XB + SZ_WA + SZ_WP + 3 * SZ_T);
  // RoPE table lives in Ao's space: needed only by gemm<1>, dead before attn writes Ao
  float2* tab = (float2*)Ao;

  hipLaunchKernelGGL(cvt_kernel, dim3(MTOK * NE / 4 / 256), dim3(256), 0, stream,
                     x, xb, MTOK * NE / 4);
  hipLaunchKernelGGL(cvt_kernel, dim3(3 * NE * NE / 4 / 256), dim3(256), 0, stream,
                     w_attn, wab, 3 * NE * NE / 4);
  hipLaunchKernelGGL(cvt_kernel, dim3(NE * NE / 4 / 256), dim3(256), 0, stream,
                     w_proj, wpb, NE * NE / 4);
  hipLaunchKernelGGL(rope_tab_kernel, dim3(TB * 32 / 256), dim3(256), 0, stream, tab);

  hipLaunchKernelGGL((gemm_bt<1>), dim3(3 * NE / 128, MTOK / 128), dim3(256), 0,
                     stream, xb, wab, nullptr, Qs, K2, V2, tab, MTOK, 3 * NE, NE);

  // 1024 blocks x 4 waves; block bx: qt = 63-(bx>>4) for bh group bx&15 (4 bh)
  hipLaunchKernelGGL(attn_kernel, dim3(1024), dim3(256), 0, stream,
                     Qs, K2, V2, Ao);

  hipLaunchKernelGGL((gemm_bt<0>), dim3(NE / 128, MTOK / 128), dim3(256), 0,
                     stream, Ao, wpb, out, nullptr, nullptr, nullptr,
                     (const float2*)nullptr, MTOK, NE, NE);
}

// Round 13
// 193.281 us; speedup vs baseline: 1.2573x; 1.2573x over previous
//
#include <hip/hip_runtime.h>
#include <hip/hip_bf16.h>

#define TB 2048
#define NH 16
#define HD 64
#define NE 1024
#define NB 4
#define BHD (NB * NH)      // 64 batch*heads
#define MTOK (NB * TB)     // 8192

typedef __attribute__((ext_vector_type(8))) short short8;
typedef __attribute__((ext_vector_type(4))) float f32x4;
typedef __attribute__((ext_vector_type(16))) float f32x16;
typedef __attribute__((ext_vector_type(4))) unsigned int u32x4;

static __device__ __forceinline__ unsigned short f2bf(float f) {
  __hip_bfloat16 h = __float2bfloat16(f);
  return __builtin_bit_cast(unsigned short, h);
}

#define GLDS(g, l)                                                              \
  __builtin_amdgcn_global_load_lds((const __attribute__((address_space(1))) void*)(g), \
                                   (__attribute__((address_space(3))) void*)(l), 16, 0, 0)

// ---------------- f32 -> bf16 convert (vectorized) ----------------
__global__ __launch_bounds__(256) void cvt_kernel(const float* __restrict__ in,
                                                  unsigned short* __restrict__ out,
                                                  int n4) {
  int i = blockIdx.x * blockDim.x + threadIdx.x;
  if (i >= n4) return;
  float4 v = reinterpret_cast<const float4*>(in)[i];
  ushort4 o;
  o.x = f2bf(v.x); o.y = f2bf(v.y); o.z = f2bf(v.z); o.w = f2bf(v.w);
  reinterpret_cast<ushort4*>(out)[i] = o;
}

// ---------------- RoPE cos/sin table: tab[t*32+j] = (cos, sin)(t * 10000^(-j/32)) ----------------
__global__ __launch_bounds__(256) void rope_tab_kernel(float2* __restrict__ tab) {
  int i = blockIdx.x * 256 + threadIdx.x;  // 0..65535
  int t = i >> 5, j = i & 31;
  float ang = (float)t * __builtin_exp2f(-(float)j * 0.41524101186092029f);
  float sv, cv;
  sincosf(ang, &sv, &cv);
  tab[i] = make_float2(cv, sv);
}

// ---------------- GEMM C = A * B^T (r10 single-buffered structure, templated tile) ----
// BM = BMW*64, BN = BNW*64 (BNW==2), waves = BMW*BNW, per-wave output 64x64 —
// identical per-wave formulas to the proven r10 kernel; only slot-loop counts
// and grid mapping generalize. QKV uses <1,4,2> (256x128, 512thr, 48KB LDS ->
// 3 blocks/CU; A-staging bytes per output element 4 -> 1.5B, grid 768 = 3/CU
// exact); proj uses <0,2,2> (= r10 exactly).
// LDS layout: slot s (16B) holds row (s>>3), logical chunk (s&7), fetched from
// source chunk (s&7)^(row&7)  [XOR swizzle; conflict-free ds_read_b128].
// EPI==1 epilogue writes K/V in FRAGMENT-MAJOR layout (4KB per 32-kv block):
//   K2 block idx = (d>>4)*512 + ((d>>3)&1)*256 + (t&31)*8 + (d&7)
//   V2 block idx = ((d>>5)*2 + ((t&31)>>4))*512 + ((t>>3)&1)*256 + (d&31)*8 + (t&7)
template <int EPI, int BMW, int BNW>
__global__ __launch_bounds__(BMW * BNW * 64) void gemm_bt(
    const unsigned short* __restrict__ Am, const unsigned short* __restrict__ Bm,
    float* __restrict__ Cout, unsigned short* __restrict__ Qo,
    unsigned short* __restrict__ Ko, unsigned short* __restrict__ Vt,
    const float2* __restrict__ Tab, int Mdim, int Ndim, int Kdim) {
  static_assert(BNW == 2, "wr/wc decode assumes BNW==2");
  constexpr int T = BMW * BNW * 64;   // threads
  constexpr int BM = BMW * 64;
  constexpr int BN = BNW * 64;
  __shared__ unsigned short As[BM * 64];
  __shared__ unsigned short Bs[BN * 64];

  const int tid = threadIdx.x;
  const int lane = tid & 63;
  const int w = tid >> 6;
  const int wr = w >> 1;
  const int wc = w & 1;

  // XCD-aware bijective swizzle (grid counts are multiples of 8)
  const int nwg = gridDim.x * gridDim.y;
  int bid = blockIdx.y * gridDim.x + blockIdx.x;
  const int cpx = nwg >> 3;
  bid = (bid & 7) * cpx + (bid >> 3);
  const int m0 = (bid / gridDim.x) * BM;
  const int n0 = (bid % gridDim.x) * BN;

  const int col16 = lane & 15;
  const int seg = lane >> 4;

  f32x4 acc[4][4];
#pragma unroll
  for (int i = 0; i < 4; ++i)
#pragma unroll
    for (int j = 0; j < 4; ++j) acc[i][j] = f32x4{0.f, 0.f, 0.f, 0.f};

  for (int kt = 0; kt < Kdim; kt += 64) {
    // stage A (BM*8/T slots/thread) and B (BN*8/T): coalesced global_load_lds,
    // wave-uniform LDS base + lane*16B; per-lane pre-swizzled global source.
#pragma unroll
    for (int i_ = 0; i_ < (BM * 8) / T; ++i_) {
      const int s = i_ * T + tid;
      const int row = s >> 3;
      const int sc = (s & 7) ^ (row & 7);
      GLDS(Am + (size_t)(m0 + row) * Kdim + kt + sc * 8,
           As + (size_t)(i_ * T + (w << 6)) * 8);
    }
#pragma unroll
    for (int i_ = 0; i_ < (BN * 8) / T; ++i_) {
      const int s = i_ * T + tid;
      const int row = s >> 3;
      const int sc = (s & 7) ^ (row & 7);
      GLDS(Bm + (size_t)(n0 + row) * Kdim + kt + sc * 8,
           Bs + (size_t)(i_ * T + (w << 6)) * 8);
    }
    __syncthreads();
#pragma unroll
    for (int kk = 0; kk < 2; ++kk) {
      short8 af[4], bfr[4];
#pragma unroll
      for (int mi = 0; mi < 4; ++mi) {
        const int row = wr * 64 + mi * 16 + col16;
        const int ch = (kk * 4 + seg) ^ (row & 7);
        af[mi] = *reinterpret_cast<const short8*>(
            reinterpret_cast<const char*>(As) + row * 128 + ch * 16);
      }
#pragma unroll
      for (int ni = 0; ni < 4; ++ni) {
        const int row = wc * 64 + ni * 16 + col16;
        const int ch = (kk * 4 + seg) ^ (row & 7);
        bfr[ni] = *reinterpret_cast<const short8*>(
            reinterpret_cast<const char*>(Bs) + row * 128 + ch * 16);
      }
#pragma unroll
      for (int mi = 0; mi < 4; ++mi)
#pragma unroll
        for (int ni = 0; ni < 4; ++ni)
          acc[mi][ni] = __builtin_amdgcn_mfma_f32_16x16x32_bf16(af[mi], bfr[ni],
                                                                acc[mi][ni], 0, 0, 0);
    }
    __syncthreads();
  }

  if (EPI == 0) {
#pragma unroll
    for (int mi = 0; mi < 4; ++mi)
#pragma unroll
      for (int ni = 0; ni < 4; ++ni) {
        const int gn = n0 + wc * 64 + ni * 16 + col16;
#pragma unroll
        for (int r = 0; r < 4; ++r) {
          const int gm = m0 + wr * 64 + mi * 16 + seg * 4 + r;
          Cout[(size_t)gm * Ndim + gn] = acc[mi][ni][r];
        }
      }
  } else {
    // qkv: n in [0,1024)=Q, [1024,2048)=K, [2048,3072)=V. BN|1024 so sec uniform.
    const int sec = n0 >> 10;
    const int cbase = (n0 & 1023) + wc * 64;  // multiple of 64
    const int h = cbase >> 6;
#pragma unroll
    for (int mi = 0; mi < 4; ++mi)
#pragma unroll
      for (int ni = 0; ni < 4; ++ni) {
        const int d = ni * 16 + col16;  // 0..63 head dim
        if (sec == 2) {
          // V2 fragment-major: 4 consecutive t (same d) stay contiguous (8B store)
          const int gm0 = m0 + wr * 64 + mi * 16 + seg * 4;
          const int b = gm0 >> 11;
          const int t0 = gm0 & 2047;
          ushort4 pv;
          pv.x = f2bf(acc[mi][ni][0]);
          pv.y = f2bf(acc[mi][ni][1]);
          pv.z = f2bf(acc[mi][ni][2]);
          pv.w = f2bf(acc[mi][ni][3]);
          const size_t vaddr = (size_t)(b * NH + h) * TB * HD + (size_t)(t0 >> 5) * 2048 +
                               ((d >> 5) * 2 + ((t0 & 31) >> 4)) * 512 +
                               ((t0 >> 3) & 1) * 256 + (d & 31) * 8 + (t0 & 7);
          *reinterpret_cast<ushort4*>(Vt + vaddr) = pv;
        } else {
          // RoPE via precomputed table: angle a_d = t * 10000^(-(d%32)/32)
          const float sgn = (d & 1) ? 1.f : -1.f;
          const int j = d & 31;
#pragma unroll
          for (int r = 0; r < 4; ++r) {
            const int gm = m0 + wr * 64 + mi * 16 + seg * 4 + r;
            const int b = gm >> 11;
            const int t = gm & 2047;
            const float v = acc[mi][ni][r];
            const float p = __shfl_xor(v, 1);  // pair partner (adjacent col)
            const float2 csv = Tab[t * 32 + j];
            float rot = v * csv.x + sgn * p * csv.y;
            if (sec == 0) {
              // fold 1/sqrt(D) AND log2(e) into Q so attn softmax can use exp2
              rot *= 0.18033688011112042f;  // 0.125 * log2(e)
              Qo[((size_t)(b * NH + h) * TB + t) * HD + d] = f2bf(rot);
            } else {
              // K2 fragment-major
              const size_t kaddr = (size_t)(b * NH + h) * TB * HD +
                                   (size_t)(t >> 5) * 2048 + (d >> 4) * 512 +
                                   ((d >> 3) & 1) * 256 + (t & 31) * 8 + (d & 7);
              Ko[kaddr] = f2bf(rot);
            }
          }
        }
      }
  }
}

// ---------------- causal flash attention v8 (r10, unchanged) ----------------
// One wave per 32-q tile, 1024 blocks x 4 waves (4096 waves). Natural VGPR ->
// 4 waves/SIMD resident without spills. LPT order: longest qt first. XCD pinned:
// bx%8 == (bx&15)%8 so each XCD serves the same 8 bh (4MB K2+V2 = one L2).
__global__ __launch_bounds__(256) void attn_kernel(
    const unsigned short* __restrict__ Q, const unsigned short* __restrict__ K2,
    const unsigned short* __restrict__ V2, unsigned short* __restrict__ Ao) {
  const int tid = threadIdx.x;
  const int lane = tid & 63;
  const int w = tid >> 6;
  const int bx = blockIdx.x;
  const int qt = 63 - (bx >> 4);        // longest q-tiles dispatched first
  const int bh = ((bx & 15) << 2) | w;  // 4 bh per block, all same qt
  const int q0 = qt << 5;
  const int l31 = lane & 31;
  const int hi = lane >> 5;
  const int qm = l31 - 4 * hi;          // diag mask: kill reg r if rowbase(r) > qm

  const unsigned short* Qb = Q + (size_t)bh * TB * HD;
  const unsigned short* K2b = K2 + (size_t)bh * TB * HD;
  const unsigned short* V2b = V2 + (size_t)bh * TB * HD;
  const int fo = hi * 256 + l31 * 8;    // per-lane offset within a fragment group

  const int batch = bh >> 4;
  const int h = bh & 15;

#define MASKDIAG(st)                                                            \
  { _Pragma("unroll") for (int r = 0; r < 16; ++r) {                            \
      const int rowb = (r & 3) + 8 * (r >> 2);                                  \
      if (rowb > qm) st[r] = -1e30f; } }

#define PVTILE(st, V0, V1, V2x, V3)                                             \
  {                                                                             \
    unsigned int wd[8];                                                         \
    _Pragma("unroll") for (int i = 0; i < 8; ++i) {                             \
      unsigned int t_;                                                          \
      asm("v_cvt_pk_bf16_f32 %0, %1, %2"                                        \
          : "=v"(t_) : "v"(st[2 * i]), "v"(st[2 * i + 1]));                     \
      wd[i] = t_;                                                               \
    }                                                                           \
    asm("v_permlane32_swap_b32 %0, %1" : "+v"(wd[0]), "+v"(wd[2]));             \
    asm("v_permlane32_swap_b32 %0, %1" : "+v"(wd[1]), "+v"(wd[3]));             \
    asm("v_permlane32_swap_b32 %0, %1" : "+v"(wd[4]), "+v"(wd[6]));             \
    asm("v_permlane32_swap_b32 %0, %1" : "+v"(wd[5]), "+v"(wd[7]));             \
    u32x4 f0 = {wd[0], wd[1], wd[2], wd[3]};                                    \
    u32x4 f1 = {wd[4], wd[5], wd[6], wd[7]};                                    \
    short8 p0 = __builtin_bit_cast(short8, f0);                                 \
    short8 p1 = __builtin_bit_cast(short8, f1);                                 \
    __builtin_amdgcn_s_setprio(1);                                              \
    o0 = __builtin_amdgcn_mfma_f32_32x32x16_bf16(V0, p0, o0, 0, 0, 0);          \
    o1 = __builtin_amdgcn_mfma_f32_32x32x16_bf16(V1, p0, o1, 0, 0, 0);          \
    o0 = __builtin_amdgcn_mfma_f32_32x32x16_bf16(V2x, p1, o0, 0, 0, 0);         \
    o1 = __builtin_amdgcn_mfma_f32_32x32x16_bf16(V3, p1, o1, 0, 0, 0);          \
    __builtin_amdgcn_s_setprio(0);                                              \
  }

  short8 qf[4];
#pragma unroll
  for (int s = 0; s < 4; ++s)
    qf[s] = *reinterpret_cast<const short8*>(
        Qb + (size_t)(q0 + l31) * HD + hi * 8 + s * 16);

  f32x16 o0, o1;
#pragma unroll
  for (int r = 0; r < 16; ++r) { o0[r] = 0.f; o1[r] = 0.f; }
  float mrow = -1e30f, lsum = 0.f;

  // preload K fragments for iter 0 (kv blocks 0 and 1) — coalesced
  short8 kf0[4], kf1[4];
#pragma unroll
  for (int s = 0; s < 4; ++s)
    kf0[s] = *reinterpret_cast<const short8*>(K2b + s * 512 + fo);
  if (q0 >= 32)
#pragma unroll
    for (int s = 0; s < 4; ++s)
      kf1[s] = *reinterpret_cast<const short8*>(K2b + 2048 + s * 512 + fo);

  const int LI = qt >> 1;
  for (int kt = 0; kt <= LI; ++kt) {
    const int kv0 = kt << 6;
    const bool two = (kv0 + 32 <= q0);

    // QK^T (S^T accumulate) with preloaded K frags
    f32x16 s0, s1;
#pragma unroll
    for (int r = 0; r < 16; ++r) { s0[r] = 0.f; s1[r] = 0.f; }
    __builtin_amdgcn_s_setprio(1);
#pragma unroll
    for (int s = 0; s < 4; ++s)
      s0 = __builtin_amdgcn_mfma_f32_32x32x16_bf16(kf0[s], qf[s], s0, 0, 0, 0);
    if (two)
#pragma unroll
      for (int s = 0; s < 4; ++s)
        s1 = __builtin_amdgcn_mfma_f32_32x32x16_bf16(kf1[s], qf[s], s1, 0, 0, 0);
    __builtin_amdgcn_s_setprio(0);

    // V frags for THIS iter (fragment-major, coalesced; consumed after softmax)
    const unsigned short* Va = V2b + (size_t)(2 * kt) * 2048 + fo;
    short8 va0 = *reinterpret_cast<const short8*>(Va);
    short8 va1 = *reinterpret_cast<const short8*>(Va + 1024);
    short8 va2 = *reinterpret_cast<const short8*>(Va + 512);
    short8 va3 = *reinterpret_cast<const short8*>(Va + 1536);
    short8 vb0, vb1, vb2, vb3;
    if (two) {
      const unsigned short* Vbp = Va + 2048;
      vb0 = *reinterpret_cast<const short8*>(Vbp);
      vb1 = *reinterpret_cast<const short8*>(Vbp + 1024);
      vb2 = *reinterpret_cast<const short8*>(Vbp + 512);
      vb3 = *reinterpret_cast<const short8*>(Vbp + 1536);
    }

    // K frags for NEXT iter (coalesced prefetch)
    if (kt < LI) {
      const unsigned short* Kn = K2b + (size_t)(2 * kt + 2) * 2048;
#pragma unroll
      for (int s = 0; s < 4; ++s)
        kf0[s] = *reinterpret_cast<const short8*>(Kn + s * 512 + fo);
      if (kv0 + 96 <= q0)
#pragma unroll
        for (int s = 0; s < 4; ++s)
          kf1[s] = *reinterpret_cast<const short8*>(Kn + 2048 + s * 512 + fo);
    }

    // causal mask on the diagonal 32x32 tile
    if (kv0 == q0) MASKDIAG(s0);
    if (two && (kv0 + 32 == q0)) MASKDIAG(s1);

    // online softmax (exp2 domain; Q pre-scaled by 0.125*log2e), defer-max,
    // tree-shaped reductions.
    float mx[8];
#pragma unroll
    for (int i = 0; i < 8; ++i) mx[i] = fmaxf(s0[2 * i], s0[2 * i + 1]);
    if (two)
#pragma unroll
      for (int i = 0; i < 8; ++i)
        mx[i] = fmaxf(mx[i], fmaxf(s1[2 * i], s1[2 * i + 1]));
#pragma unroll
    for (int i = 0; i < 4; ++i) mx[i] = fmaxf(mx[i], mx[i + 4]);
    float pm = fmaxf(fmaxf(mx[0], mx[1]), fmaxf(mx[2], mx[3]));
    pm = fmaxf(pm, __shfl_xor(pm, 32));
    if (!__all(pm - mrow <= 8.f)) {
      const float mn = fmaxf(mrow, pm);
      const float fs = __builtin_exp2f(mrow - mn);
      mrow = mn;
      lsum *= fs;
#pragma unroll
      for (int r = 0; r < 16; ++r) { o0[r] *= fs; o1[r] *= fs; }
    }
    float sm[8];
#pragma unroll
    for (int i = 0; i < 8; ++i) {
      s0[2 * i] = __builtin_exp2f(s0[2 * i] - mrow);
      s0[2 * i + 1] = __builtin_exp2f(s0[2 * i + 1] - mrow);
      sm[i] = s0[2 * i] + s0[2 * i + 1];
    }
    if (two)
#pragma unroll
      for (int i = 0; i < 8; ++i) {
        s1[2 * i] = __builtin_exp2f(s1[2 * i] - mrow);
        s1[2 * i + 1] = __builtin_exp2f(s1[2 * i + 1] - mrow);
        sm[i] += s1[2 * i] + s1[2 * i + 1];
      }
#pragma unroll
    for (int i = 0; i < 4; ++i) sm[i] += sm[i + 4];
    float rs = (sm[0] + sm[1]) + (sm[2] + sm[3]);
    rs += __shfl_xor(rs, 32);
    lsum += rs;

    PVTILE(s0, va0, va1, va2, va3);
    if (two) PVTILE(s1, vb0, vb1, vb2, vb3);
  }

  // epilogue: normalize (lsum lane-uniform per q) and store bf16 to Ao[B][T][E]
  const float inv = 1.f / lsum;
  unsigned short* Aor = Ao + ((size_t)(batch * TB + q0 + l31)) * NE + (h << 6);
#pragma unroll
  for (int dt = 0; dt < 2; ++dt) {
#pragma unroll
    for (int qd = 0; qd < 4; ++qd) {
      ushort4 pk;
      pk.x = f2bf((dt ? o1[4 * qd + 0] : o0[4 * qd + 0]) * inv);
      pk.y = f2bf((dt ? o1[4 * qd + 1] : o0[4 * qd + 1]) * inv);
      pk.z = f2bf((dt ? o1[4 * qd + 2] : o0[4 * qd + 2]) * inv);
      pk.w = f2bf((dt ? o1[4 * qd + 3] : o0[4 * qd + 3]) * inv);
      *reinterpret_cast<ushort4*>(Aor + dt * 32 + 8 * qd + 4 * hi) = pk;
    }
  }
#undef MASKDIAG
#undef PVTILE
}

// ---------------- launch ----------------
extern "C" void kernel_launch(void* const* d_in, const int* in_sizes, int n_in,
                              void* d_out, int out_size, void* d_ws, size_t ws_size,
                              hipStream_t stream) {
  const float* x = (const float*)d_in[0];
  const float* w_attn = (const float*)d_in[1];
  const float* w_proj = (const float*)d_in[2];
  float* out = (float*)d_out;
  char* ws = (char*)d_ws;

  const size_t SZ_XB = (size_t)MTOK * NE * 2;        // 16 MiB
  const size_t SZ_WA = (size_t)3 * NE * NE * 2;      // 6 MiB
  const size_t SZ_WP = (size_t)NE * NE * 2;          // 2 MiB
  const size_t SZ_T = (size_t)BHD * TB * HD * 2;     // 16 MiB

  unsigned short* xb = (unsigned short*)(ws);
  unsigned short* wab = (unsigned short*)(ws + SZ_XB);
  unsigned short* wpb = (unsigned short*)(ws + SZ_XB + SZ_WA);
  unsigned short* Qs = (unsigned short*)(ws + SZ_XB + SZ_WA + SZ_WP);
  unsigned short* K2 = (unsigned short*)(ws + SZ_XB + SZ_WA + SZ_WP + SZ_T);
  unsigned short* V2 = (unsigned short*)(ws + SZ_XB + SZ_WA + SZ_WP + 2 * SZ_T);
  unsigned short* Ao = (unsigned short*)(ws + SZ_XB + SZ_WA + SZ_WP + 3 * SZ_T);
  // RoPE table lives in Ao's space: needed only by gemm<1>, dead before attn writes Ao
  float2* tab = (float2*)Ao;

  hipLaunchKernelGGL(cvt_kernel, dim3(MTOK * NE / 4 / 256), dim3(256), 0, stream,
                     x, xb, MTOK * NE / 4);
  hipLaunchKernelGGL(cvt_kernel, dim3(3 * NE * NE / 4 / 256), dim3(256), 0, stream,
                     w_attn, wab, 3 * NE * NE / 4);
  hipLaunchKernelGGL(cvt_kernel, dim3(NE * NE / 4 / 256), dim3(256), 0, stream,
                     w_proj, wpb, NE * NE / 4);
  hipLaunchKernelGGL(rope_tab_kernel, dim3(TB * 32 / 256), dim3(256), 0, stream, tab);

  // QKV: 256x128 tile, 512 threads, grid 24x32 = 768 blocks = 3/CU exact
  hipLaunchKernelGGL((gemm_bt<1, 4, 2>), dim3(3 * NE / 128, MTOK / 256), dim3(512),
                     0, stream, xb, wab, nullptr, Qs, K2, V2, tab, MTOK, 3 * NE, NE);

  // 1024 blocks x 4 waves; block bx: qt = 63-(bx>>4) for bh group bx&15 (4 bh)
  hipLaunchKernelGGL(attn_kernel, dim3(1024), dim3(256), 0, stream,
                     Qs, K2, V2, Ao);

  // proj: exact r10 128x128 config
  hipLaunchKernelGGL((gemm_bt<0, 2, 2>), dim3(NE / 128, MTOK / 128), dim3(256),
                     0, stream, Ao, wpb, out, nullptr, nullptr, nullptr,
                     (const float2*)nullptr, MTOK, NE, NE);
}